// Round 11
// baseline (181.174 us; speedup 1.0000x reference)
//
#include <hip/hip_runtime.h>

// Mamba2D: B=4, C=128, H=W=64 (L=4096), D_INNER=256, D_STATE=16, DT_RANK=8, D_CONV=4
// 6-kernel pipeline; scan-side tensors d-major ([b][d][l]), GEMM-side l-major.
// This round: scan t-loops PARTIALLY unrolled (x4) to fit I$; all t-indexed state
// moved to LDS (rule #20: no runtime-indexed register arrays).
//  prep:     W2b=bf16(in_proj@proj); wTb48; Woutb; Aneg
//  gemm_xz:  bf16 MFMA, 64-l tile x both o-halves (x read once) -> d-major xT, zT
//  mid:      fused conv4+silu -> x_dbl MFMA -> scan1 (x read from swizzled LDS)
//  scan2:    chunk prefix (fp32)
//  scan3:    replay + y (x/z staged in LDS) -> LDS transpose -> l-major bf16 y2b
//  gemm_out: bf16 MFMA, out = Wout @ y2 + x

#define NCHUNK 128
#define CLEN 32

using s16x8 = __attribute__((ext_vector_type(8))) short;
using f32x4 = __attribute__((ext_vector_type(4))) float;

__device__ inline unsigned short f2bf(float f) {
  unsigned u = __float_as_uint(f);
  u = u + 0x7FFF + ((u >> 16) & 1);
  return (unsigned short)(u >> 16);
}
__device__ inline float bfu(unsigned short v) {
  return __uint_as_float((unsigned)v << 16);
}

// ---------------- prep ----------------
__global__ void prep_kernel(const float* __restrict__ proj_w,
                            const float* __restrict__ in_proj_w,
                            const float* __restrict__ x_proj_w,
                            const float* __restrict__ out_proj_w,
                            const float* __restrict__ A_log,
                            unsigned short* __restrict__ W2b,
                            unsigned short* __restrict__ wTb48,
                            unsigned short* __restrict__ Woutb,
                            float* __restrict__ Aneg) {
  int idx = blockIdx.x * blockDim.x + threadIdx.x;
  if (idx < 65536) {
    int o = idx >> 7, c = idx & 127;
    float acc = 0.f;
    #pragma unroll 4
    for (int i = 0; i < 128; ++i)
      acc += in_proj_w[o * 128 + i] * proj_w[i * 128 + c];
    W2b[idx] = f2bf(acc);
  } else if (idx < 65536 + 12288) {
    int t = idx - 65536;
    int j = t >> 8, k = t & 255;
    wTb48[t] = (j < 40) ? f2bf(x_proj_w[j * 256 + k]) : (unsigned short)0;
  } else if (idx < 65536 + 12288 + 32768) {
    int t = idx - (65536 + 12288);
    Woutb[t] = f2bf(out_proj_w[t]);
  } else if (idx < 65536 + 12288 + 32768 + 4096) {
    int t = idx - (65536 + 12288 + 32768);
    Aneg[t] = -__expf(A_log[t]);
  }
}

// ---------------- xz GEMM: 64-l tile, both o-halves, x read once ----------------
__global__ __launch_bounds__(256) void gemm_xz_kernel(
    const float* __restrict__ x, const unsigned short* __restrict__ W2b,
    unsigned short* __restrict__ xT, unsigned short* __restrict__ zT) {
  __shared__ __align__(16) unsigned short At[64 * 128];   // 16 KB
  __shared__ __align__(16) unsigned short Bt[256 * 128];  // 64 KB
  int blk = blockIdx.x;              // 256: b*64 + ltile
  int b = blk >> 6;
  int l0 = (blk & 63) * 64;
  int t = threadIdx.x;
  #pragma unroll
  for (int j = 0; j < 8; ++j) {
    int flat = t + j * 256;          // 0..2047
    int c = flat >> 4, lq = (flat & 15) << 2;
    float4 v = *reinterpret_cast<const float4*>(
        &x[((size_t)(b * 128 + c)) * 4096 + l0 + lq]);
    float vv[4] = {v.x, v.y, v.z, v.w};
    #pragma unroll
    for (int e = 0; e < 4; ++e) {
      int l = lq + e;
      int g = (c >> 3) ^ ((l & 7) << 1);
      At[l * 128 + g * 8 + (c & 7)] = f2bf(vv[e]);
    }
  }
  int ln = t & 63, w = t >> 6;
  for (int half = 0; half < 2; ++half) {
    int o0 = half * 256;
    __syncthreads();
    #pragma unroll
    for (int j = 0; j < 16; ++j) {
      int flat = t + j * 256;
      int row = flat >> 4, gB = flat & 15;
      s16x8 v = *reinterpret_cast<const s16x8*>(&W2b[(size_t)(o0 + row) * 128 + gB * 8]);
      int g = gB ^ ((row & 7) << 1);
      *reinterpret_cast<s16x8*>(&Bt[row * 128 + g * 8]) = v;
    }
    __syncthreads();
    f32x4 acc[16] = {};
    #pragma unroll
    for (int ks = 0; ks < 4; ++ks) {
      int gk = ks * 4 + (ln >> 4);
      int ar = w * 16 + (ln & 15);
      s16x8 a = *reinterpret_cast<const s16x8*>(&At[ar * 128 + (gk ^ ((ar & 7) << 1)) * 8]);
      #pragma unroll
      for (int nt = 0; nt < 16; ++nt) {
        int br = nt * 16 + (ln & 15);
        s16x8 bb = *reinterpret_cast<const s16x8*>(&Bt[br * 128 + (gk ^ ((br & 7) << 1)) * 8]);
        acc[nt] = __builtin_amdgcn_mfma_f32_16x16x32_bf16(a, bb, acc[nt], 0, 0, 0);
      }
    }
    unsigned short* T = half ? zT : xT;
    #pragma unroll
    for (int nt = 0; nt < 16; ++nt) {
      int d = nt * 16 + (ln & 15);
      int lrow = l0 + w * 16 + ((ln >> 4) << 2);
      ushort4 h4{f2bf(acc[nt][0]), f2bf(acc[nt][1]), f2bf(acc[nt][2]), f2bf(acc[nt][3])};
      *reinterpret_cast<ushort4*>(&T[((size_t)(b * 256 + d)) * 4096 + lrow]) = h4;
    }
  }
}

// ---------------- mid: fused conv4+silu -> x_dbl MFMA -> scan1 ----------------
__global__ __launch_bounds__(256) void mid_kernel(
    const unsigned short* __restrict__ xT, const float* __restrict__ conv_w,
    const float* __restrict__ conv_b, const unsigned short* __restrict__ wTb48,
    const float* __restrict__ dt_proj_w, const float* __restrict__ dt_proj_b,
    const float* __restrict__ Aneg,
    unsigned short* __restrict__ xcT, float* __restrict__ xdbl48,
    float* __restrict__ Ssum, float* __restrict__ chH) {
  __shared__ __align__(16) unsigned short sxc[32 * 256];   // 16 KB, swizzled bf16
  __shared__ __align__(16) unsigned short sBt[48 * 256];   // 24 KB, swizzled bf16
  __shared__ __align__(16) float pxd[4 * 32 * 49];         // ~25 KB partials (pad 49)
  int blk = blockIdx.x;               // b*128 + c
  int b = blk >> 7, c = blk & 127;
  int l0 = c * CLEN;
  int d = threadIdx.x;
  // ---- conv ----
  size_t rowbase = ((size_t)(b * 256 + d)) * 4096;
  float wf[40];
  {
    const s16x8* src = reinterpret_cast<const s16x8*>(&xT[rowbase + l0 - 8]);
    #pragma unroll
    for (int i = 0; i < 5; ++i) {
      s16x8 v = src[i];
      #pragma unroll
      for (int e = 0; e < 8; ++e) wf[i * 8 + e] = bfu((unsigned short)v[e]);
    }
    if (l0 == 0) { wf[5] = 0.f; wf[6] = 0.f; wf[7] = 0.f; }
  }
  float w0 = conv_w[d * 4 + 0], w1 = conv_w[d * 4 + 1];
  float w2 = conv_w[d * 4 + 2], w3 = conv_w[d * 4 + 3];
  float cb = conv_b[d];
  unsigned short xcb16[32];
  #pragma unroll
  for (int r = 0; r < 32; ++r) {
    float acc = cb + w3 * wf[8 + r] + w2 * wf[7 + r] + w1 * wf[6 + r] + w0 * wf[5 + r];
    float s = acc * (1.f / (1.f + __expf(-acc)));
    xcb16[r] = f2bf(s);
  }
  #pragma unroll
  for (int i = 0; i < 4; ++i) {
    s16x8 v;
    #pragma unroll
    for (int e = 0; e < 8; ++e) v[e] = (short)xcb16[i * 8 + e];
    *reinterpret_cast<s16x8*>(&xcT[rowbase + l0 + i * 8]) = v;
  }
  #pragma unroll
  for (int l = 0; l < 32; ++l)
    sxc[l * 256 + (((d >> 3) ^ ((l & 7) << 1)) << 3) + (d & 7)] = xcb16[l];
  #pragma unroll
  for (int it = 0; it < 6; ++it) {
    int f = d + it * 256;
    int row = f >> 5, g0 = f & 31;
    s16x8 v = *reinterpret_cast<const s16x8*>(&wTb48[(size_t)row * 256 + g0 * 8]);
    int g = g0 ^ ((row & 7) << 1);
    *reinterpret_cast<s16x8*>(&sBt[row * 256 + g * 8]) = v;
  }
  __syncthreads();
  // ---- x_dbl MFMA: M=32, N=48, K=256; wave w takes k-quarter ----
  {
    int ln = d & 63, w = d >> 6;
    f32x4 acc[2][3] = {};
    #pragma unroll
    for (int kk = 0; kk < 2; ++kk) {
      int ks = w * 2 + kk;
      int gk = ks * 4 + (ln >> 4);
      #pragma unroll
      for (int m = 0; m < 2; ++m) {
        int ar = m * 16 + (ln & 15);
        s16x8 a = *reinterpret_cast<const s16x8*>(&sxc[ar * 256 + (gk ^ ((ar & 7) << 1)) * 8]);
        #pragma unroll
        for (int nt = 0; nt < 3; ++nt) {
          int br = nt * 16 + (ln & 15);
          s16x8 bb = *reinterpret_cast<const s16x8*>(&sBt[br * 256 + (gk ^ ((br & 7) << 1)) * 8]);
          acc[m][nt] = __builtin_amdgcn_mfma_f32_16x16x32_bf16(a, bb, acc[m][nt], 0, 0, 0);
        }
      }
    }
    #pragma unroll
    for (int m = 0; m < 2; ++m)
      #pragma unroll
      for (int nt = 0; nt < 3; ++nt)
        #pragma unroll
        for (int r = 0; r < 4; ++r) {
          int row = m * 16 + (ln >> 4) * 4 + r;
          int col = nt * 16 + (ln & 15);
          pxd[(w * 32 + row) * 49 + col] = acc[m][nt][r];
        }
  }
  __syncthreads();
  // ---- reduce partials, write xdbl48 ----
  #pragma unroll
  for (int it = 0; it < 6; ++it) {
    int idx = d + it * 256;          // 0..1535
    int l = idx / 48, j = idx - l * 48;
    float s = pxd[l * 49 + j] + pxd[(32 + l) * 49 + j] +
              pxd[(64 + l) * 49 + j] + pxd[(96 + l) * 49 + j];
    pxd[l * 49 + j] = s;
    xdbl48[(size_t)blk * 1536 + idx] = s;
  }
  __syncthreads();
  // ---- scan1: partial unroll; x from sxc (LDS), dt_r/B from pxd (LDS) ----
  float wrow[8];
  *reinterpret_cast<float4*>(&wrow[0]) = *reinterpret_cast<const float4*>(&dt_proj_w[d * 8]);
  *reinterpret_cast<float4*>(&wrow[4]) = *reinterpret_cast<const float4*>(&dt_proj_w[d * 8 + 4]);
  float bb = dt_proj_b[d];
  float An[16];
  #pragma unroll
  for (int q = 0; q < 4; ++q)
    *reinterpret_cast<float4*>(&An[q * 4]) =
        *reinterpret_cast<const float4*>(&Aneg[d * 16 + q * 4]);
  float h[16] = {};
  float S = 0.f;
  #pragma unroll 4
  for (int t = 0; t < CLEN; ++t) {
    float a = bb;
    #pragma unroll
    for (int q = 0; q < 8; ++q) a += pxd[t * 49 + q] * wrow[q];
    float dlv = fmaxf(a, 0.f) + __logf(1.f + __expf(-fabsf(a)));
    S += dlv;
    float xval = bfu(sxc[t * 256 + (((d >> 3) ^ ((t & 7) << 1)) << 3) + (d & 7)]);
    float dlx = dlv * xval;
    #pragma unroll
    for (int n = 0; n < 16; ++n)
      h[n] = __expf(dlv * An[n]) * h[n] + dlx * pxd[t * 49 + 8 + n];
  }
  int p = b * 256 + d;
  Ssum[c * 1024 + p] = S;
  size_t base = ((size_t)(c * 1024 + p)) * 16;
  #pragma unroll
  for (int q = 0; q < 4; ++q) {
    float4 v{h[q*4+0], h[q*4+1], h[q*4+2], h[q*4+3]};
    *reinterpret_cast<float4*>(&chH[base + q * 4]) = v;
  }
}

// ---------------- scan phase 2: chunk prefix ----------------
__global__ void scan2_kernel(const float* __restrict__ Aneg,
                             const float* __restrict__ Ssum,
                             const float* __restrict__ chH,
                             float* __restrict__ chS) {
  int q = blockIdx.x * blockDim.x + threadIdx.x;  // 0..16383
  int p = q >> 4, n = q & 15;
  int d = p & 255;
  float An = Aneg[d * 16 + n];
  float h = 0.f;
  #pragma unroll 8
  for (int c = 0; c < NCHUNK; ++c) {
    size_t idx = ((size_t)(c * 1024 + p)) * 16 + n;
    float S = Ssum[c * 1024 + p];
    float hl = chH[idx];
    chS[idx] = h;
    h = __expf(An * S) * h + hl;
  }
}

// ---------------- scan phase 3: partial unroll, x/z staged in LDS ----------------
__global__ __launch_bounds__(256) void scan3_kernel(
    const unsigned short* __restrict__ xcT, const unsigned short* __restrict__ zT,
    const float* __restrict__ xdbl48,
    const float* __restrict__ dt_proj_w, const float* __restrict__ dt_proj_b,
    const float* __restrict__ Aneg, const float* __restrict__ chS,
    const float* __restrict__ Dvec, unsigned short* __restrict__ y2b) {
  __shared__ __align__(16) float lBC[CLEN][32];
  __shared__ __align__(16) float sdtr[CLEN][8];
  __shared__ unsigned short sx[CLEN][256];
  __shared__ unsigned short sz[CLEN][256];
  __shared__ unsigned short sy[CLEN][256];
  int blk = blockIdx.x;
  int b = blk >> 7, c = blk & 127;
  int bl0 = blk * CLEN;
  int tid = threadIdx.x;
  {
    int t0 = tid >> 3, q = (tid & 7) << 2;
    *reinterpret_cast<float4*>(&lBC[t0][q]) =
        *reinterpret_cast<const float4*>(&xdbl48[(size_t)(bl0 + t0) * 48 + 8 + q]);
    if (tid < 64) {
      int t1 = tid >> 1, q1 = (tid & 1) << 2;
      *reinterpret_cast<float4*>(&sdtr[t1][q1]) =
          *reinterpret_cast<const float4*>(&xdbl48[(size_t)(bl0 + t1) * 48 + q1]);
    }
  }
  int d = tid;
  // stage x/z d-major -> LDS l-major (write: fixed t, consecutive d -> conflict-free)
  {
    size_t rb = ((size_t)(b * 256 + d)) * 4096 + c * CLEN;
    const s16x8* sxp = reinterpret_cast<const s16x8*>(&xcT[rb]);
    const s16x8* szp = reinterpret_cast<const s16x8*>(&zT[rb]);
    #pragma unroll
    for (int i = 0; i < 4; ++i) {
      s16x8 vx = sxp[i], vz = szp[i];
      #pragma unroll
      for (int e = 0; e < 8; ++e) {
        sx[i * 8 + e][d] = (unsigned short)vx[e];
        sz[i * 8 + e][d] = (unsigned short)vz[e];
      }
    }
  }
  float wrow[8];
  *reinterpret_cast<float4*>(&wrow[0]) = *reinterpret_cast<const float4*>(&dt_proj_w[d * 8]);
  *reinterpret_cast<float4*>(&wrow[4]) = *reinterpret_cast<const float4*>(&dt_proj_w[d * 8 + 4]);
  float bb = dt_proj_b[d];
  float An[16];
  #pragma unroll
  for (int q = 0; q < 4; ++q)
    *reinterpret_cast<float4*>(&An[q * 4]) =
        *reinterpret_cast<const float4*>(&Aneg[d * 16 + q * 4]);
  int p = b * 256 + d;
  float h[16];
  {
    size_t base = ((size_t)(c * 1024 + p)) * 16;
    #pragma unroll
    for (int q = 0; q < 4; ++q) {
      float4 v = *reinterpret_cast<const float4*>(&chS[base + q * 4]);
      h[q*4+0] = v.x; h[q*4+1] = v.y; h[q*4+2] = v.z; h[q*4+3] = v.w;
    }
  }
  float Dd = Dvec[d];
  __syncthreads();
  #pragma unroll 4
  for (int t = 0; t < CLEN; ++t) {
    float a = bb;
    #pragma unroll
    for (int q = 0; q < 8; ++q) a += sdtr[t][q] * wrow[q];
    float dlv = fmaxf(a, 0.f) + __logf(1.f + __expf(-fabsf(a)));
    float xval = bfu(sx[t][d]);
    float dlx = dlv * xval;
    float y = 0.f;
    #pragma unroll
    for (int n = 0; n < 16; ++n) {
      h[n] = __expf(dlv * An[n]) * h[n] + dlx * lBC[t][n];
      y += h[n] * lBC[t][16 + n];
    }
    float z = bfu(sz[t][d]);
    float sil = z * (1.f / (1.f + __expf(-z)));
    sy[t][d] = f2bf((y + xval * Dd) * sil);
  }
  __syncthreads();
  #pragma unroll
  for (int it = 0; it < 4; ++it) {
    int idx = tid + it * 256;
    int l = idx >> 5, ds8 = (idx & 31) * 8;
    s16x8 v = *reinterpret_cast<const s16x8*>(&sy[l][ds8]);
    *reinterpret_cast<s16x8*>(&y2b[((size_t)(bl0 + l)) * 256 + ds8]) = v;
  }
}

// ---------------- out GEMM via bf16 MFMA: out = Wout @ y2 + x ----------------
__global__ __launch_bounds__(256) void gemm_out_kernel(
    const unsigned short* __restrict__ y2b, const unsigned short* __restrict__ Woutb,
    const float* __restrict__ x, float* __restrict__ out) {
  __shared__ __align__(16) unsigned short At[64 * 256];
  __shared__ __align__(16) unsigned short Bt[128 * 256];
  int m0 = blockIdx.x * 64;
  int b = m0 >> 12, l0 = m0 & 4095;
  int t = threadIdx.x;
  #pragma unroll
  for (int it = 0; it < 8; ++it) {
    int f = t + it * 256;
    int row = f >> 5, g0 = f & 31;
    s16x8 v = *reinterpret_cast<const s16x8*>(&y2b[(size_t)(m0 + row) * 256 + g0 * 8]);
    int g = g0 ^ ((row & 7) << 1);
    *reinterpret_cast<s16x8*>(&At[row * 256 + g * 8]) = v;
  }
  #pragma unroll
  for (int it = 0; it < 16; ++it) {
    int f = t + it * 256;
    int row = f >> 5, g0 = f & 31;
    s16x8 v = *reinterpret_cast<const s16x8*>(&Woutb[(size_t)row * 256 + g0 * 8]);
    int g = g0 ^ ((row & 7) << 1);
    *reinterpret_cast<s16x8*>(&Bt[row * 256 + g * 8]) = v;
  }
  __syncthreads();
  int ln = t & 63, wm = t >> 6;
  f32x4 acc[8] = {};
  #pragma unroll
  for (int ks = 0; ks < 8; ++ks) {
    int gk = ks * 4 + (ln >> 4);
    int ar = wm * 16 + (ln & 15);
    s16x8 a = *reinterpret_cast<const s16x8*>(&At[ar * 256 + (gk ^ ((ar & 7) << 1)) * 8]);
    #pragma unroll
    for (int nt = 0; nt < 8; ++nt) {
      int br = nt * 16 + (ln & 15);
      s16x8 bb = *reinterpret_cast<const s16x8*>(&Bt[br * 256 + (gk ^ ((br & 7) << 1)) * 8]);
      acc[nt] = __builtin_amdgcn_mfma_f32_16x16x32_bf16(a, bb, acc[nt], 0, 0, 0);
    }
  }
  #pragma unroll
  for (int nt = 0; nt < 8; ++nt) {
    int cc = nt * 16 + (ln & 15);
    size_t base = ((size_t)(b * 128 + cc)) * 4096 + l0 + wm * 16 + ((ln >> 4) << 2);
    float4 xr = *reinterpret_cast<const float4*>(&x[base]);
    float4 o{acc[nt][0] + xr.x, acc[nt][1] + xr.y, acc[nt][2] + xr.z, acc[nt][3] + xr.w};
    *reinterpret_cast<float4*>(&out[base]) = o;
  }
}

extern "C" void kernel_launch(void* const* d_in, const int* in_sizes, int n_in,
                              void* d_out, int out_size, void* d_ws, size_t ws_size,
                              hipStream_t stream) {
  const float* x         = (const float*)d_in[0];
  const float* proj_w    = (const float*)d_in[1];
  const float* in_proj_w = (const float*)d_in[2];
  const float* conv_w    = (const float*)d_in[3];
  const float* conv_b    = (const float*)d_in[4];
  const float* x_proj_w  = (const float*)d_in[5];
  const float* dt_proj_w = (const float*)d_in[6];
  const float* dt_proj_b = (const float*)d_in[7];
  const float* A_log     = (const float*)d_in[8];
  const float* Dvec      = (const float*)d_in[9];
  const float* out_proj_w= (const float*)d_in[10];

  float* ws = (float*)d_ws;
  float*          Aneg   = ws;                                  // 4096 f
  unsigned short* W2b    = (unsigned short*)(ws + 4096);        // 32768 f
  unsigned short* wTb48  = (unsigned short*)(ws + 36864);       // 6144 f
  unsigned short* Woutb  = (unsigned short*)(ws + 43008);       // 16384 f
  // 32-f pad before xT: mid reads xT[l0-8] at b=0,d=0,l0=0
  unsigned short* xT     = (unsigned short*)(ws + 59424);       // 2097152 f
  unsigned short* zT     = (unsigned short*)(ws + 2156576);     // 2097152 f
  unsigned short* xcT    = (unsigned short*)(ws + 4253728);     // 2097152 f
  float*          xdbl48 = ws + 6350880;                        // 786432 f
  float*          Ssum   = ws + 7137312;                        // 131072 f
  float*          chH    = ws + 7268384;                        // 2097152 f
  float*          chS    = ws + 9365536;                        // 2097152 f
  unsigned short* y2b    = (unsigned short*)(ws + 11462688);    // 2097152 f
  float* out = (float*)d_out;                                   // total ~54 MB

  prep_kernel<<<448, 256, 0, stream>>>(proj_w, in_proj_w, x_proj_w, out_proj_w, A_log,
                                       W2b, wTb48, Woutb, Aneg);
  gemm_xz_kernel<<<256, 256, 0, stream>>>(x, W2b, xT, zT);
  mid_kernel<<<512, 256, 0, stream>>>(xT, conv_w, conv_b, wTb48, dt_proj_w, dt_proj_b,
                                      Aneg, xcT, xdbl48, Ssum, chH);
  scan2_kernel<<<128, 128, 0, stream>>>(Aneg, Ssum, chH, chS);
  scan3_kernel<<<512, 256, 0, stream>>>(xcT, zT, xdbl48, dt_proj_w, dt_proj_b, Aneg,
                                        chS, Dvec, y2b);
  gemm_out_kernel<<<256, 256, 0, stream>>>(y2b, Woutb, x, out);
}